// Round 9
// baseline (180.451 us; speedup 1.0000x reference)
//
#include <hip/hip_runtime.h>
#include <stdint.h>
#include <math.h>

#define HFM 64
#define WFM 128
#define CFM 128
#define BN 2
#define HWFM (HFM*WFM)          // 8192
#define NPIX (BN*HWFM)          // 16384
#define KQ 6000
#define KQP 6144                // padded to 48*128 (rows 6000..6143 zero)
#define NNEG 60
#define NE (NPIX*NNEG)          // 983040
#define EHALF_U 491520u
#define MSHIFT 15.0f
#define LOG2E 1.4426950408889634f

typedef _Float16 f16_8 __attribute__((ext_vector_type(8)));
typedef _Float16 f16_2 __attribute__((ext_vector_type(2)));
typedef float f32_4 __attribute__((ext_vector_type(4)));

// ---------------- JAX threefry2x32 (bit-exact) ----------------
__host__ __device__ __forceinline__ void threefry2x32(uint32_t k0, uint32_t k1,
                                                      uint32_t x0, uint32_t x1,
                                                      uint32_t* o0, uint32_t* o1) {
  uint32_t ks2 = k0 ^ k1 ^ 0x1BD11BDAu;
  x0 += k0; x1 += k1;
#define TFR(r) { x0 += x1; x1 = (x1 << (r)) | (x1 >> (32 - (r))); x1 ^= x0; }
  TFR(13) TFR(15) TFR(26) TFR(6)
  x0 += k1;  x1 += ks2 + 1u;
  TFR(17) TFR(29) TFR(16) TFR(24)
  x0 += ks2; x1 += k0 + 2u;
  TFR(13) TFR(15) TFR(26) TFR(6)
  x0 += k0;  x1 += k1 + 3u;
  TFR(17) TFR(29) TFR(16) TFR(24)
  x0 += k1;  x1 += ks2 + 4u;
  TFR(13) TFR(15) TFR(26) TFR(6)
  x0 += ks2; x1 += k0 + 5u;
#undef TFR
  *o0 = x0; *o1 = x1;
}

// grid_sample coordinate helper (reference op order)
__device__ __forceinline__ void gs_coord(float t, float halfdim, float maxc,
                                         int* i0, int* i1, float* w) {
  float g = 2.0f * t - 1.0f;
  float x = (g + 1.0f) * halfdim - 0.5f;
  x = fminf(fmaxf(x, 0.0f), maxc);
  float f = floorf(x);
  *i0 = (int)f;
  *w = x - f;
  *i1 = (int)fminf(f + 1.0f, maxc);
}

// ====== k_A: mask (first, latency-bound) + qprep + queue transpose + feature
// transpose. blocks [0,64): mask; [64,88): qeb prep (+acc/count zero);
// [88,472): queue T; [472,2520): feat T.
__global__ __launch_bounds__(256) void k_A(
    const float* __restrict__ ref, const float* __restrict__ tgt,
    const float* __restrict__ queue,
    const float* __restrict__ target_l, const float* __restrict__ target_r,
    _Float16* __restrict__ refTf, _Float16* __restrict__ tgtTf,
    _Float16* __restrict__ queueTf, float2* __restrict__ qeb,
    float* __restrict__ maskArr, float* __restrict__ xr,
    double* __restrict__ dacc, int* __restrict__ dctr, int* __restrict__ count) {
  __shared__ float tile[64][35];
  int blk = blockIdx.x;
  int tid = threadIdx.x;
  if (blk < 64) {
    // mask: one thread per pixel
    int p = blk * 256 + tid;
    int b = p >> 13;
    int rem = p & (HWFM - 1);
    int i = rem >> 7, j = rem & 127;
    const float stepx = 1.0f / 127.0f, stepy = 1.0f / 63.0f;
    float xb = (j == 127) ? 1.0f : j * stepx;
    float yb = (i == 63) ? 1.0f : i * stepy;
    const float* tl = target_l + (size_t)b * 256 * 512;
    const float* tr = target_r + (size_t)b * 256 * 512;
    float dl = tl[(4 * i) * 512 + 4 * j] * 0.25f;
    int y0i, y1i; float wy;
    gs_coord(yb, 32.0f, 63.0f, &y0i, &y1i, &wy);
    float t = xb - dl * (1.0f / 128.0f);
    int x0i, x1i; float wx;
    gs_coord(t, 64.0f, 127.0f, &x0i, &x1i, &wx);
    auto innerv = [&](int y, int x) -> float {
      float xbx = (x == 127) ? 1.0f : x * stepx;
      float drv = tr[(4 * y) * 512 + 4 * x] * 0.25f;
      float ti = xbx + drv * (1.0f / 128.0f);
      float g = 2.0f * ti - 1.0f;
      float ix2 = fminf(fmaxf((g + 1.0f) * 64.0f - 0.5f, 0.0f), 127.0f);
      float x0f = floorf(ix2);
      float wxp = ix2 - x0f;
      float x1f = fminf(x0f + 1.0f, 127.0f);
      return x0f * (1.0f - wxp) + x1f * wxp;
    };
    float v00 = innerv(y0i, x0i), v01 = innerv(y0i, x1i);
    float v10 = innerv(y1i, x0i), v11 = innerv(y1i, x1i);
    float l2r2l = v00 * (1.0f - wx) * (1.0f - wy) + v01 * wx * (1.0f - wy)
                + v10 * (1.0f - wx) * wy + v11 * wx * wy;
    bool masko = fabsf((float)j - l2r2l) < 3.0f;
    bool mk = masko && (dl > 0.0f) && (t >= 0.0f);
    maskArr[p] = mk ? 1.0f : 0.0f;
    xr[p] = t * 128.0f;   // exact: t*2^7
  } else if (blk < 88) {
    if (blk == 64 && tid == 0) { *dacc = 0.0; *dctr = 0; *count = 0; }
    int k = (blk - 64) * 256 + tid;
    if (k < KQP) {
      if (k >= KQ) { qeb[k] = make_float2(0.0f, -1000.0f); }
      else {
        float ss = 0.0f;
        for (int c = 0; c < CFM; c++) { float v = queue[c * KQ + k]; ss += v * v; }
        float qi = 1.0f / fmaxf(sqrtf(ss), 1e-12f);
        qeb[k] = make_float2(qi * (LOG2E / 0.07f), -MSHIFT * LOG2E);
      }
    }
  } else if (blk < 472) {
    // queue transpose: 64c x 32n tiles; 192 n-tiles x 2 c-tiles
    int q = blk - 88;
    int cy = q / 192, nx = q - cy * 192;
    int n0 = nx * 32, c0 = cy * 64;
    int c = tid >> 2, qq = tid & 3;
    const float* sp = queue + (size_t)(c0 + c) * KQ + n0 + qq * 4;
    if (n0 + 32 <= KQ) {
      float4 v0 = *(const float4*)sp;
      float4 v1 = *(const float4*)(sp + 16);
      tile[c][qq * 4 + 0] = v0.x; tile[c][qq * 4 + 1] = v0.y;
      tile[c][qq * 4 + 2] = v0.z; tile[c][qq * 4 + 3] = v0.w;
      tile[c][qq * 4 + 16] = v1.x; tile[c][qq * 4 + 17] = v1.y;
      tile[c][qq * 4 + 18] = v1.z; tile[c][qq * 4 + 19] = v1.w;
    } else {
#pragma unroll
      for (int k = 0; k < 4; k++) {
        int n = n0 + qq * 4 + k;
        tile[c][qq * 4 + k] = (n < KQ) ? sp[k] : 0.0f;
        tile[c][qq * 4 + 16 + k] = (n + 16 < KQ) ? sp[16 + k] : 0.0f;
      }
    }
    __syncthreads();
    int x = tid >> 3, j8 = tid & 7;
    f16_8 o;
#pragma unroll
    for (int k = 0; k < 8; k++) o[k] = (_Float16)tile[j8 * 8 + k][x];
    *(f16_8*)(queueTf + (size_t)(n0 + x) * CFM + c0 + j8 * 8) = o;
  } else {
    // feature transpose: z in {ref b0, ref b1, tgt b0, tgt b1}
    int fblk = blk - 472;
    int z = fblk >> 9, rem2 = fblk & 511;
    int cy = rem2 >> 8, xt = rem2 & 255;
    int x0 = xt * 32, c0 = cy * 64;
    int arr = z >> 1, b = z & 1;
    const float* src = (arr == 0 ? ref : tgt) + (size_t)b * CFM * HWFM;
    _Float16* dst = (arr == 0 ? refTf : tgtTf) + (size_t)b * HWFM * CFM;
    int c = tid >> 2, qq = tid & 3;
    const float* sp = src + (size_t)(c0 + c) * HWFM + x0 + qq * 4;
    float4 v0 = *(const float4*)sp;
    float4 v1 = *(const float4*)(sp + 16);
    tile[c][qq * 4 + 0] = v0.x; tile[c][qq * 4 + 1] = v0.y;
    tile[c][qq * 4 + 2] = v0.z; tile[c][qq * 4 + 3] = v0.w;
    tile[c][qq * 4 + 16] = v1.x; tile[c][qq * 4 + 17] = v1.y;
    tile[c][qq * 4 + 18] = v1.z; tile[c][qq * 4 + 19] = v1.w;
    __syncthreads();
    int x = tid >> 3, j8 = tid & 7;
    f16_8 o;
#pragma unroll
    for (int k = 0; k < 8; k++) o[k] = (_Float16)tile[j8 * 8 + k][x];
    *(f16_8*)(dst + (size_t)(x0 + x) * CFM + c0 + j8 * 8) = o;
  }
}

// ====== k_B: compact [0,64) parallel ballot+atomic; colstats [64,128);
// prelude [128, 128+4096) p-indexed ======
__global__ __launch_bounds__(256) void k_B(
    const _Float16* __restrict__ refTf, const _Float16* __restrict__ tgtTf,
    _Float16* __restrict__ QTf, float* __restrict__ stats,
    const float* __restrict__ maskArr, const float* __restrict__ xr,
    float* __restrict__ S, float* __restrict__ logit0,
    int* __restrict__ count, int* __restrict__ list) {
  int blk = blockIdx.x;
  int tid = threadIdx.x;
  int lane = tid & 63;
  if (blk < 64) {
    // compact: 256 pixels/block, unordered list via wave ballot + atomic base
    int p = blk * 256 + tid;
    bool m = maskArr[p] > 0.0f;
    unsigned long long bits = __ballot(m);
    int nact = __popcll(bits);
    int prefix = __popcll(bits & ((1ull << lane) - 1ull));
    int base = 0;
    if (lane == 0 && nact) base = atomicAdd(count, nact);
    base = __shfl(base, 0, 64);
    if (m) list[base + prefix] = p;
  } else if (blk < 128) {
    int sub = tid >> 6;
    int xg = (blk - 64) * 4 + sub;
    int b = xg >> 7, x = xg & 127;
    int xp = min(x + 1, 127);
    int c2 = lane * 2;
    int base = b * HWFM;
    f16_2 c0  = *(const f16_2*)(tgtTf + (size_t)(base + x) * CFM + c2);
    f16_2 c1  = *(const f16_2*)(tgtTf + (size_t)(base + WFM + x) * CFM + c2);
    f16_2 c0p = *(const f16_2*)(tgtTf + (size_t)(base + xp) * CFM + c2);
    f16_2 c1p = *(const f16_2*)(tgtTf + (size_t)(base + WFM + xp) * CFM + c2);
    float a0 = (float)c0[0], a1 = (float)c0[1];
    float b0 = (float)c1[0], b1 = (float)c1[1];
    float p0 = (float)c0p[0], p1 = (float)c0p[1];
    float q0 = (float)c1p[0], q1 = (float)c1p[1];
    float s[7];
    s[0] = a0 * a0 + a1 * a1;
    s[1] = a0 * b0 + a1 * b1;
    s[2] = b0 * b0 + b1 * b1;
    s[3] = a0 * p0 + a1 * p1;
    s[4] = a0 * q0 + a1 * q1;
    s[5] = b0 * p0 + b1 * p1;
    s[6] = b0 * q0 + b1 * q1;
#pragma unroll
    for (int o = 32; o; o >>= 1)
#pragma unroll
      for (int k = 0; k < 7; k++) s[k] += __shfl_xor(s[k], o, 64);
    if (lane == 0) {
      float* st = stats + (size_t)xg * 8;
#pragma unroll
      for (int k = 0; k < 7; k++) st[k] = s[k];
      st[7] = 0.0f;
    }
  } else {
    // prelude: wave per pixel p (p-indexed), early-exit masked
    int wave = tid >> 6;
    int p = (blk - 128) * 4 + wave;
    float mk = maskArr[p];
    if (mk == 0.0f) return;
    int b = p >> 13;
    int rem = p & (HWFM - 1);
    int i = rem >> 7;
    const float stepy = 1.0f / 63.0f;
    float yb = (i == 63) ? 1.0f : i * stepy;
    float t = xr[p] * (1.0f / 128.0f);   // exact recovery
    int y0i, y1i; float wy;
    gs_coord(yb, 32.0f, 63.0f, &y0i, &y1i, &wy);
    int x0i, x1i; float wx;
    gs_coord(t, 64.0f, 127.0f, &x0i, &x1i, &wx);

    int c2 = lane * 2;
    f16_2 q2 = *(const f16_2*)(refTf + (size_t)p * CFM + c2);
    int bo = b * HWFM;
    f16_2 a2 = *(const f16_2*)(tgtTf + (size_t)(bo + y0i * WFM + x0i) * CFM + c2);
    f16_2 b2 = *(const f16_2*)(tgtTf + (size_t)(bo + y0i * WFM + x1i) * CFM + c2);
    f16_2 cc2 = *(const f16_2*)(tgtTf + (size_t)(bo + y1i * WFM + x0i) * CFM + c2);
    f16_2 d2 = *(const f16_2*)(tgtTf + (size_t)(bo + y1i * WFM + x1i) * CFM + c2);

    float w00 = (1.0f - wx) * (1.0f - wy), w01 = wx * (1.0f - wy);
    float w10 = (1.0f - wx) * wy,          w11 = wx * wy;
    float q0 = (float)q2[0], q1 = (float)q2[1];
    float v0 = w00 * (float)a2[0] + w01 * (float)b2[0] + w10 * (float)cc2[0] + w11 * (float)d2[0];
    float v1 = w00 * (float)a2[1] + w01 * (float)b2[1] + w10 * (float)cc2[1] + w11 * (float)d2[1];

    float s0 = q0 * q0 + q1 * q1;
    float s1 = q0 * v0 + q1 * v1;
    float s2 = v0 * v0 + v1 * v1;
#pragma unroll
    for (int o = 32; o; o >>= 1) {
      s0 += __shfl_xor(s0, o, 64);
      s1 += __shfl_xor(s1, o, 64);
      s2 += __shfl_xor(s2, o, 64);
    }
    float inv = 1.0f / fmaxf(sqrtf(s0), 1e-12f);
    f16_2 qw; qw[0] = (_Float16)(q0 * inv); qw[1] = (_Float16)(q1 * inv);
    *(f16_2*)(QTf + (size_t)p * CFM + c2) = qw;
    if (lane == 0) {
      float lpos = (s1 * inv) / fmaxf(sqrtf(s2), 1e-12f);
      float lg0 = lpos / 0.07f;
      logit0[p] = lg0;
      S[p] = expf(lg0 - MSHIFT);
    }
  }
}

// ====== k_gemm v7: 32-row tiles (2x parallelism vs v4 at CONSTANT L2
// traffic). grid 4096 1-D: split = bid & 7 (XCD-affine, same as v4),
// row-block = bid >> 3 (512 blocks of 32 list slots). Unlike r5's 16-col-
// split (which duplicated the A-gather and lost 6 us), row-splitting keeps
// total A-gather and total staged-B bytes exactly constant (166x8KB vs
// 83x16KB chunks) while doubling active blocks: ~2.6 -> ~5.2 per CU, so the
// 4 resident slots stay full. Wave grid 2M-rows x 4N-waves: wave tile
// 32 rows x 16 cols, each B fragment still feeds 2 MFMAs. Per-chunk LDS
// Bs = 2 x 8 KB dbuf; XOR-swizzled global_load_lds staging; qb loaded
// before the stage (vmcnt ordering, r8-verified).
__global__ __launch_bounds__(256, 4) void k_gemm(
    const _Float16* __restrict__ QTf,     // [NPIX][128] (p-indexed)
    const _Float16* __restrict__ queueTf, // [6144][128]
    const _Float16* __restrict__ tgtTf,   // [NPIX][128]
    const float2* __restrict__ qeb,       // [6144]
    float* __restrict__ S, float* __restrict__ D,
    const int* __restrict__ count, const int* __restrict__ list) {
  __shared__ _Float16 Bs[2][32 * CFM];    // 2 x 8 KB
  __shared__ float Srow[32];
  int tid = threadIdx.x;
  int cnt = *count;
  int split = blockIdx.x & 7;             // XCD-affine column split
  int slot0 = (blockIdx.x >> 3) * 32;
  if (slot0 >= cnt) return;
  int wave = tid >> 6, lane = tid & 63;
  int quad = lane >> 4, l16 = lane & 15;
  int wn = wave;                          // 4 N-waves, 16 cols each
  int dbatch = split >> 2;                // this split's D chunk: batch
  int dxoff = (split & 3) * 64;           // and pixel/column offset

  if (tid < 32) Srow[tid] = 0.0f;

  // stage one 32-row B chunk (8 KB): 2 DMA insts/thread, 4 B-rows each.
  // LDS linear dest; swizzle via global source: LDS[r][c] = G[r][c ^ (r&7)]
  int lrow = lane >> 4, lchunk = lane & 15;
  auto stage = [&](const _Float16* bsrc, int buf) {
#pragma unroll
    for (int i = 0; i < 2; i++) {
      int rb = wave * 8 + i * 4;
      int r = rb + lrow;
      const _Float16* g = bsrc + (size_t)r * CFM + ((lchunk ^ (r & 7)) << 3);
      __builtin_amdgcn_global_load_lds(
          (const __attribute__((address_space(1))) void*)g,
          (__attribute__((address_space(3))) void*)(&Bs[buf][rb * CFM]),
          16, 0, 0);
    }
  };
  // B panel base for chunk ic: 0..11 = l_q cols, 12 = this split's D chunk
  // (D chunk uses first 32 of the 64 pixel-columns? No: D chunk is 64 cols
  //  wide in v4; with 32-row tiles the chunk is still 64 COLS x 128 K —
  //  col-width is unchanged; only the ROW tile shrank.)
  auto bpanel = [&](int ic) -> const _Float16* {
    if (ic < 12) return queueTf + (size_t)(split * 768 + ic * 64) * CFM;
    return tgtTf + ((size_t)dbatch * HWFM + dxoff) * CFM;
  };
  // NOTE on stage geometry: a chunk is 64 B-rows x 128 f16 = 16 KB in v4;
  // here each chunk stages only rows [0,32) per half? NO — the chunk must
  // cover all 64 cols. Resolution: stage TWO 4-KB halves per chunk via the
  // 2-inst loop over 32 rows... but 64 cols x 128 K = 64 B-rows. With a
  // 32x128 Bs we process each 64-col chunk as TWO sub-chunks of 32 cols.
  // => 26 sub-chunks total, LDS 2x8KB, same schedule logic below.
  auto bsub = [&](int sc) -> const _Float16* {       // sub-chunk 0..25
    int ic = sc >> 1, half = sc & 1;
    return bpanel(ic) + (size_t)(half * 32) * CFM;
  };

  stage(bsub(0), 0);

  // A fragments via list indirection: all 32 rows (shared by the 4 waves)
  f16_8 Af[2][4];
#pragma unroll
  for (int mt = 0; mt < 2; mt++) {
    int prow = list[min(slot0 + mt * 16 + l16, cnt - 1)];
    const _Float16* arow = QTf + (size_t)prow * CFM + quad * 8;
#pragma unroll
    for (int ks = 0; ks < 4; ks++)
      Af[mt][ks] = *(const f16_8*)(arow + ks * 32);
  }
  // row batch ids (consumed by the D chunk's masked write)
  int pbv[2][4];
#pragma unroll
  for (int mt = 0; mt < 2; mt++)
#pragma unroll
    for (int r = 0; r < 4; r++)
      pbv[mt][r] = list[min(slot0 + mt * 16 + quad * 4 + r, cnt - 1)] >> 13;

  __syncthreads();
  int cur = 0;
  float rowsum[2][4] = {{0.0f,0.0f,0.0f,0.0f},{0.0f,0.0f,0.0f,0.0f}};

  for (int sc = 0; sc < 26; sc++) {
    int ic = sc >> 1, half = sc & 1;
    // qb FIRST: older than the stage DMA (vmcnt ordering)
    float2 qb;
    bool isD = (ic == 12);
    if (!isD) {
      int n0 = split * 768 + ic * 64 + half * 32 + (wn & 1) * 16;
      qb = qeb[n0 + l16];
    }
    if (sc + 1 < 26) stage(bsub(sc + 1), cur ^ 1);
    // wave wn covers cols (wn&1)*16 within its 32-col half IF wn<2 handles
    // half? No: all 4 waves share the 32-col sub-chunk: wave wn covers
    // cols [(wn&1)*16, +16) and rows via mt as before; waves 0/1 and 2/3
    // duplicate cols — instead give waves 2/3 the SAME cols but accumulate
    // only once. Simplest correct mapping: waves 0,1 cover the two 16-col
    // groups; waves 2,3 cover the same groups for the OTHER K-half? K is
    // fully looped by ks. To keep all 4 waves busy without duplication,
    // map: colgrp = wn & 1, rowgrp = wn >> 1 — waves 2,3 take rows 16..31
    // as their mt=0. So wave tile = 16 rows x 16 cols, mt loop = 1.
    int colgrp = wn & 1, rowgrp = wn >> 1;
    f32_4 acc;
    acc = (f32_4){0.0f, 0.0f, 0.0f, 0.0f};
    f32_4 acc2 = (f32_4){0.0f, 0.0f, 0.0f, 0.0f};   // second row-group half
    // each wave: rows [rowgrp*16, +16) x cols [colgrp*16, +16):
#pragma unroll
    for (int ks = 0; ks < 4; ks++) {
      int brow = colgrp * 16 + l16;
      f16_8 Bk = *(const f16_8*)(&Bs[cur][brow * CFM + ((ks * 32 + quad * 8) ^ ((brow & 7) * 8))]);
      acc = __builtin_amdgcn_mfma_f32_16x16x32_f16(Af[rowgrp][ks], Bk, acc, 0, 0, 0);
    }
    (void)acc2;
    if (!isD) {
      // qb above was loaded for colgrp = wn&1 ✓ (n0 used (wn&1)*16)
#pragma unroll
      for (int r = 0; r < 4; r++)
        rowsum[rowgrp][r] += exp2f(fmaf(acc[r], qb.x, qb.y));
    } else {
#pragma unroll
      for (int r = 0; r < 4; r++) {
        int sl = slot0 + rowgrp * 16 + quad * 4 + r;
        int colL = dxoff + half * 32 + colgrp * 16 + l16;
        if (sl < cnt && pbv[rowgrp][r] == dbatch)
          D[(size_t)sl * 256 + colL] = acc[r];
      }
    }
    __syncthreads();
    cur ^= 1;
  }

  // rowsum[rowgrp][r] holds this wave's 16-col partial for rows
  // rowgrp*16 + quad*4 + r; reduce over l16, then cross-wave via Srow.
#pragma unroll
  for (int r = 0; r < 4; r++) {
    int rowgrp = wn >> 1;
    float vv = rowsum[rowgrp][r];
    vv += __shfl_xor(vv, 1);
    vv += __shfl_xor(vv, 2);
    vv += __shfl_xor(vv, 4);
    vv += __shfl_xor(vv, 8);
    if (l16 == 0) atomicAdd(&Srow[rowgrp * 16 + quad * 4 + r], vv);
  }
  __syncthreads();
  if (tid < 32) {
    int pr = slot0 + tid;
    if (pr < cnt) atomicAdd(&S[list[pr]], Srow[tid]);
  }
}

// -------- negatives: wave-per-pixel, scalar via D + stats decomposition ----
__global__ __launch_bounds__(256) void k_negatives_lite(
    const float* __restrict__ D, const float* __restrict__ stats,
    const float* __restrict__ xr, float* __restrict__ S,
    const int* __restrict__ count, const int* __restrict__ list,
    uint32_t k1a, uint32_t k1b, uint32_t k2a, uint32_t k2b) {
  int tid = threadIdx.x;
  int wave = tid >> 6, lane = tid & 63;
  int cnt = *count;
  int slot = blockIdx.x * 4 + wave;
  if (slot >= cnt) return;
  int p = list[slot];
  int b = p >> 13;
  float esum = 0.0f;
  if (lane < NNEG) {
    uint32_t e = (uint32_t)(p * NNEG + lane);
    uint32_t h0, h1;
    threefry2x32(k1a, k1b, e, e + (uint32_t)NE, &h0, &h1);
    uint32_t off = ((h0 % 24u) * 16u + (h1 % 24u)) % 24u;
    float mag = (float)(1u + off);
    uint32_t ub;
    {
      uint32_t a, bm;
      if (e < EHALF_U) { threefry2x32(k2a, k2b, e, e + EHALF_U, &a, &bm); ub = a; }
      else             { threefry2x32(k2a, k2b, e - EHALF_U, e, &a, &bm); ub = bm; }
    }
    float u = __uint_as_float((ub >> 9) | 0x3F800000u) - 1.0f;
    float sg = (u > 0.5f) ? 1.0f : ((u < 0.5f) ? -1.0f : 0.0f);

    float v = xr[p] + mag * sg;
    float r = fmodf(v, 128.0f);
    if (r < 0.0f) r += 128.0f;
    float fx = r * (1.0f / 128.0f);
    float fy = fx * (1.0f / 64.0f);
    int x0i, x1i, y0i, y1i; float wx, wy;
    gs_coord(fx, 64.0f, 127.0f, &x0i, &x1i, &wx);
    gs_coord(fy, 32.0f, 63.0f, &y0i, &y1i, &wy);

    const float* Dp = D + (size_t)slot * 256;
    float d00 = Dp[x0i], d01 = Dp[x1i];
    float d10 = Dp[128 + x0i], d11 = Dp[128 + x1i];
    float u0 = 1.0f - wy, u1 = wy;
    float dv0 = u0 * d00 + u1 * d10;
    float dv1 = u0 * d01 + u1 * d11;
    float dot = (1.0f - wx) * dv0 + wx * dv1;

    const float* st0 = stats + (size_t)(b * 128 + x0i) * 8;
    const float* st1 = stats + (size_t)(b * 128 + x1i) * 8;
    float4 sa = *(const float4*)st0;
    float4 sb = *(const float4*)(st0 + 4);
    float4 sc = *(const float4*)st1;
    float a0 = u0 * u0, a1 = u0 * u1, a2 = u1 * u1;
    float nB0 = a0 * sa.x + 2.0f * a1 * sa.y + a2 * sa.z;
    float nB1 = a0 * sc.x + 2.0f * a1 * sc.y + a2 * sc.z;
    float cB  = a0 * sa.w + a1 * (sb.x + sb.y) + a2 * sb.z;
    float wx0 = 1.0f - wx;
    float nsq = wx0 * wx0 * nB0 + 2.0f * wx * wx0 * cB + wx * wx * nB1;
    float ln = dot / fmaxf(sqrtf(fmaxf(nsq, 0.0f)), 1e-12f);
    esum = __expf(ln * (1.0f / 0.07f) - MSHIFT);
  }
#pragma unroll
  for (int o = 32; o; o >>= 1) esum += __shfl_xor(esum, o, 64);
  if (lane == 0) atomicAdd(&S[p], esum);
}

// -------- finalize: 16 blocks, per-block deterministic tree, cross-block
// double atomics. 16 device-scope fences total (cheap); do NOT scale this
// to thousands of blocks — r7 measured ~27 ns/block-fence serialized
// (per-XCD L2 writeback) = 112 us at 4096 blocks.
__global__ __launch_bounds__(1024) void k_finalize(
    const float* __restrict__ S, const float* __restrict__ logit0,
    const float* __restrict__ maskArr, float* __restrict__ out,
    double* __restrict__ dacc, int* __restrict__ dctr) {
  int tid = threadIdx.x;
  const float cmask = logf(6061.0f);
  int p = blockIdx.x * 1024 + tid;
  float term = (maskArr[p] > 0.0f) ? (logf(S[p]) + MSHIFT - logit0[p]) : cmask;
  double acc = (double)term;
#pragma unroll
  for (int off = 32; off; off >>= 1) acc += __shfl_down(acc, off, 64);
  __shared__ double sd[16];
  if ((tid & 63) == 0) sd[tid >> 6] = acc;
  __syncthreads();
  if (tid == 0) {
    double tot = 0.0;
    for (int w = 0; w < 16; w++) tot += sd[w];
    atomicAdd(dacc, tot);
    __threadfence();
    int old = atomicAdd(dctr, 1);
    if (old == 15) {
      __threadfence();
      out[0] = (float)(*(volatile double*)dacc / (double)NPIX);
    }
  }
}

extern "C" void kernel_launch(void* const* d_in, const int* in_sizes, int n_in,
                              void* d_out, int out_size, void* d_ws, size_t ws_size,
                              hipStream_t stream) {
  const float* ref   = (const float*)d_in[0];
  const float* tgt   = (const float*)d_in[1];
  const float* tl    = (const float*)d_in[2];
  const float* tr    = (const float*)d_in[3];
  const float* queue = (const float*)d_in[4];
  float* out = (float*)d_out;
  float* ws = (float*)d_ws;

  float2* qeb = (float2*)ws;                 // 6144 float2 -> 12288 floats
  float* S    = ws + 12288;                  // 16384
  float* lg0  = ws + 28672;                  // 16384
  float* mk   = ws + 45056;                  // 16384
  float* xr   = ws + 61440;                  // 16384 -> 77824
  int* count  = (int*)(ws + 77824);          // 1
  double* dacc = (double*)(ws + 77826);      // 8B-aligned (77826*4 % 8 == 0)
  int* dctr   = (int*)(ws + 77828);          // 1
  int* list   = (int*)(ws + 77840);          // 16384 -> 94224
  _Float16* QTf     = (_Float16*)(ws + 94464);    // NPIX*128 f16 (p-indexed)
  _Float16* queueTf = (_Float16*)(ws + 1143040);  // 6144*128 f16
  _Float16* tgtTf   = (_Float16*)(ws + 1536256);  // NPIX*128 f16
  _Float16* refTf   = (_Float16*)(ws + 2584832);  // NPIX*128 f16
  float* stats = ws + 3633408;                    // 2048
  float* D     = ws + 3635456;                    // NPIX*256 f32

  // JAX: k1, k2 = split(key(1234))
  uint32_t b0o0, b0o1, b1o0, b1o1;
  threefry2x32(0u, 1234u, 0u, 2u, &b0o0, &b0o1);
  threefry2x32(0u, 1234u, 1u, 3u, &b1o0, &b1o1);
  uint32_t k1a = b0o0, k1b = b1o0, k2a = b0o1, k2b = b1o1;

  k_A<<<dim3(2520), dim3(256), 0, stream>>>(ref, tgt, queue, tl, tr,
                                            refTf, tgtTf, queueTf, qeb, mk, xr,
                                            dacc, dctr, count);
  k_B<<<dim3(128 + 4096), dim3(256), 0, stream>>>(refTf, tgtTf, QTf, stats,
                                                  mk, xr, S, lg0, count, list);
  // 8 XCD-affine splits x 512 row-blocks of 32, 1-D grid (split = bid & 7)
  k_gemm<<<dim3(4096), dim3(256), 0, stream>>>(QTf, queueTf, tgtTf, qeb,
                                               S, D, count, list);
  k_negatives_lite<<<dim3(NPIX / 4), dim3(256), 0, stream>>>(D, stats, xr, S, count, list,
                                                             k1a, k1b, k2a, k2b);
  k_finalize<<<dim3(16), dim3(1024), 0, stream>>>(S, lg0, mk, out, dacc, dctr);
}

// Round 10
// 114.374 us; speedup vs baseline: 1.5777x; 1.5777x over previous
//
#include <hip/hip_runtime.h>
#include <stdint.h>
#include <math.h>

#define HFM 64
#define WFM 128
#define CFM 128
#define BN 2
#define HWFM (HFM*WFM)          // 8192
#define NPIX (BN*HWFM)          // 16384
#define KQ 6000
#define KQP 6144                // padded to 48*128 (rows 6000..6143 zero)
#define NNEG 60
#define NE (NPIX*NNEG)          // 983040
#define EHALF_U 491520u
#define MSHIFT 15.0f
#define LOG2E 1.4426950408889634f

typedef _Float16 f16_8 __attribute__((ext_vector_type(8)));
typedef _Float16 f16_2 __attribute__((ext_vector_type(2)));
typedef float f32_4 __attribute__((ext_vector_type(4)));

// ---------------- JAX threefry2x32 (bit-exact) ----------------
__host__ __device__ __forceinline__ void threefry2x32(uint32_t k0, uint32_t k1,
                                                      uint32_t x0, uint32_t x1,
                                                      uint32_t* o0, uint32_t* o1) {
  uint32_t ks2 = k0 ^ k1 ^ 0x1BD11BDAu;
  x0 += k0; x1 += k1;
#define TFR(r) { x0 += x1; x1 = (x1 << (r)) | (x1 >> (32 - (r))); x1 ^= x0; }
  TFR(13) TFR(15) TFR(26) TFR(6)
  x0 += k1;  x1 += ks2 + 1u;
  TFR(17) TFR(29) TFR(16) TFR(24)
  x0 += ks2; x1 += k0 + 2u;
  TFR(13) TFR(15) TFR(26) TFR(6)
  x0 += k0;  x1 += k1 + 3u;
  TFR(17) TFR(29) TFR(16) TFR(24)
  x0 += k1;  x1 += ks2 + 4u;
  TFR(13) TFR(15) TFR(26) TFR(6)
  x0 += ks2; x1 += k0 + 5u;
#undef TFR
  *o0 = x0; *o1 = x1;
}

// grid_sample coordinate helper (reference op order)
__device__ __forceinline__ void gs_coord(float t, float halfdim, float maxc,
                                         int* i0, int* i1, float* w) {
  float g = 2.0f * t - 1.0f;
  float x = (g + 1.0f) * halfdim - 0.5f;
  x = fminf(fmaxf(x, 0.0f), maxc);
  float f = floorf(x);
  *i0 = (int)f;
  *w = x - f;
  *i1 = (int)fminf(f + 1.0f, maxc);
}

// ====== k_A: mask (first, latency-bound) + qprep + queue transpose + feature
// transpose. blocks [0,64): mask; [64,88): qeb prep (+acc/count zero);
// [88,472): queue T; [472,2520): feat T.
__global__ __launch_bounds__(256) void k_A(
    const float* __restrict__ ref, const float* __restrict__ tgt,
    const float* __restrict__ queue,
    const float* __restrict__ target_l, const float* __restrict__ target_r,
    _Float16* __restrict__ refTf, _Float16* __restrict__ tgtTf,
    _Float16* __restrict__ queueTf, float2* __restrict__ qeb,
    float* __restrict__ maskArr, float* __restrict__ xr,
    double* __restrict__ dacc, int* __restrict__ dctr, int* __restrict__ count) {
  __shared__ float tile[64][35];
  int blk = blockIdx.x;
  int tid = threadIdx.x;
  if (blk < 64) {
    // mask: one thread per pixel
    int p = blk * 256 + tid;
    int b = p >> 13;
    int rem = p & (HWFM - 1);
    int i = rem >> 7, j = rem & 127;
    const float stepx = 1.0f / 127.0f, stepy = 1.0f / 63.0f;
    float xb = (j == 127) ? 1.0f : j * stepx;
    float yb = (i == 63) ? 1.0f : i * stepy;
    const float* tl = target_l + (size_t)b * 256 * 512;
    const float* tr = target_r + (size_t)b * 256 * 512;
    float dl = tl[(4 * i) * 512 + 4 * j] * 0.25f;
    int y0i, y1i; float wy;
    gs_coord(yb, 32.0f, 63.0f, &y0i, &y1i, &wy);
    float t = xb - dl * (1.0f / 128.0f);
    int x0i, x1i; float wx;
    gs_coord(t, 64.0f, 127.0f, &x0i, &x1i, &wx);
    auto innerv = [&](int y, int x) -> float {
      float xbx = (x == 127) ? 1.0f : x * stepx;
      float drv = tr[(4 * y) * 512 + 4 * x] * 0.25f;
      float ti = xbx + drv * (1.0f / 128.0f);
      float g = 2.0f * ti - 1.0f;
      float ix2 = fminf(fmaxf((g + 1.0f) * 64.0f - 0.5f, 0.0f), 127.0f);
      float x0f = floorf(ix2);
      float wxp = ix2 - x0f;
      float x1f = fminf(x0f + 1.0f, 127.0f);
      return x0f * (1.0f - wxp) + x1f * wxp;
    };
    float v00 = innerv(y0i, x0i), v01 = innerv(y0i, x1i);
    float v10 = innerv(y1i, x0i), v11 = innerv(y1i, x1i);
    float l2r2l = v00 * (1.0f - wx) * (1.0f - wy) + v01 * wx * (1.0f - wy)
                + v10 * (1.0f - wx) * wy + v11 * wx * wy;
    bool masko = fabsf((float)j - l2r2l) < 3.0f;
    bool mk = masko && (dl > 0.0f) && (t >= 0.0f);
    maskArr[p] = mk ? 1.0f : 0.0f;
    xr[p] = t * 128.0f;   // exact: t*2^7
  } else if (blk < 88) {
    if (blk == 64 && tid == 0) { *dacc = 0.0; *dctr = 0; *count = 0; }
    int k = (blk - 64) * 256 + tid;
    if (k < KQP) {
      if (k >= KQ) { qeb[k] = make_float2(0.0f, -1000.0f); }
      else {
        float ss = 0.0f;
        for (int c = 0; c < CFM; c++) { float v = queue[c * KQ + k]; ss += v * v; }
        float qi = 1.0f / fmaxf(sqrtf(ss), 1e-12f);
        qeb[k] = make_float2(qi * (LOG2E / 0.07f), -MSHIFT * LOG2E);
      }
    }
  } else if (blk < 472) {
    // queue transpose: 64c x 32n tiles; 192 n-tiles x 2 c-tiles
    int q = blk - 88;
    int cy = q / 192, nx = q - cy * 192;
    int n0 = nx * 32, c0 = cy * 64;
    int c = tid >> 2, qq = tid & 3;
    const float* sp = queue + (size_t)(c0 + c) * KQ + n0 + qq * 4;
    if (n0 + 32 <= KQ) {
      float4 v0 = *(const float4*)sp;
      float4 v1 = *(const float4*)(sp + 16);
      tile[c][qq * 4 + 0] = v0.x; tile[c][qq * 4 + 1] = v0.y;
      tile[c][qq * 4 + 2] = v0.z; tile[c][qq * 4 + 3] = v0.w;
      tile[c][qq * 4 + 16] = v1.x; tile[c][qq * 4 + 17] = v1.y;
      tile[c][qq * 4 + 18] = v1.z; tile[c][qq * 4 + 19] = v1.w;
    } else {
#pragma unroll
      for (int k = 0; k < 4; k++) {
        int n = n0 + qq * 4 + k;
        tile[c][qq * 4 + k] = (n < KQ) ? sp[k] : 0.0f;
        tile[c][qq * 4 + 16 + k] = (n + 16 < KQ) ? sp[16 + k] : 0.0f;
      }
    }
    __syncthreads();
    int x = tid >> 3, j8 = tid & 7;
    f16_8 o;
#pragma unroll
    for (int k = 0; k < 8; k++) o[k] = (_Float16)tile[j8 * 8 + k][x];
    *(f16_8*)(queueTf + (size_t)(n0 + x) * CFM + c0 + j8 * 8) = o;
  } else {
    // feature transpose: z in {ref b0, ref b1, tgt b0, tgt b1}
    int fblk = blk - 472;
    int z = fblk >> 9, rem2 = fblk & 511;
    int cy = rem2 >> 8, xt = rem2 & 255;
    int x0 = xt * 32, c0 = cy * 64;
    int arr = z >> 1, b = z & 1;
    const float* src = (arr == 0 ? ref : tgt) + (size_t)b * CFM * HWFM;
    _Float16* dst = (arr == 0 ? refTf : tgtTf) + (size_t)b * HWFM * CFM;
    int c = tid >> 2, qq = tid & 3;
    const float* sp = src + (size_t)(c0 + c) * HWFM + x0 + qq * 4;
    float4 v0 = *(const float4*)sp;
    float4 v1 = *(const float4*)(sp + 16);
    tile[c][qq * 4 + 0] = v0.x; tile[c][qq * 4 + 1] = v0.y;
    tile[c][qq * 4 + 2] = v0.z; tile[c][qq * 4 + 3] = v0.w;
    tile[c][qq * 4 + 16] = v1.x; tile[c][qq * 4 + 17] = v1.y;
    tile[c][qq * 4 + 18] = v1.z; tile[c][qq * 4 + 19] = v1.w;
    __syncthreads();
    int x = tid >> 3, j8 = tid & 7;
    f16_8 o;
#pragma unroll
    for (int k = 0; k < 8; k++) o[k] = (_Float16)tile[j8 * 8 + k][x];
    *(f16_8*)(dst + (size_t)(x0 + x) * CFM + c0 + j8 * 8) = o;
  }
}

// ====== k_B: compact [0,64) parallel ballot+atomic; colstats [64,128);
// prelude [128, 128+4096) p-indexed ======
__global__ __launch_bounds__(256) void k_B(
    const _Float16* __restrict__ refTf, const _Float16* __restrict__ tgtTf,
    _Float16* __restrict__ QTf, float* __restrict__ stats,
    const float* __restrict__ maskArr, const float* __restrict__ xr,
    float* __restrict__ S, float* __restrict__ logit0,
    int* __restrict__ count, int* __restrict__ list) {
  int blk = blockIdx.x;
  int tid = threadIdx.x;
  int lane = tid & 63;
  if (blk < 64) {
    // compact: 256 pixels/block, unordered list via wave ballot + atomic base
    int p = blk * 256 + tid;
    bool m = maskArr[p] > 0.0f;
    unsigned long long bits = __ballot(m);
    int nact = __popcll(bits);
    int prefix = __popcll(bits & ((1ull << lane) - 1ull));
    int base = 0;
    if (lane == 0 && nact) base = atomicAdd(count, nact);
    base = __shfl(base, 0, 64);
    if (m) list[base + prefix] = p;
  } else if (blk < 128) {
    int sub = tid >> 6;
    int xg = (blk - 64) * 4 + sub;
    int b = xg >> 7, x = xg & 127;
    int xp = min(x + 1, 127);
    int c2 = lane * 2;
    int base = b * HWFM;
    f16_2 c0  = *(const f16_2*)(tgtTf + (size_t)(base + x) * CFM + c2);
    f16_2 c1  = *(const f16_2*)(tgtTf + (size_t)(base + WFM + x) * CFM + c2);
    f16_2 c0p = *(const f16_2*)(tgtTf + (size_t)(base + xp) * CFM + c2);
    f16_2 c1p = *(const f16_2*)(tgtTf + (size_t)(base + WFM + xp) * CFM + c2);
    float a0 = (float)c0[0], a1 = (float)c0[1];
    float b0 = (float)c1[0], b1 = (float)c1[1];
    float p0 = (float)c0p[0], p1 = (float)c0p[1];
    float q0 = (float)c1p[0], q1 = (float)c1p[1];
    float s[7];
    s[0] = a0 * a0 + a1 * a1;
    s[1] = a0 * b0 + a1 * b1;
    s[2] = b0 * b0 + b1 * b1;
    s[3] = a0 * p0 + a1 * p1;
    s[4] = a0 * q0 + a1 * q1;
    s[5] = b0 * p0 + b1 * p1;
    s[6] = b0 * q0 + b1 * q1;
#pragma unroll
    for (int o = 32; o; o >>= 1)
#pragma unroll
      for (int k = 0; k < 7; k++) s[k] += __shfl_xor(s[k], o, 64);
    if (lane == 0) {
      float* st = stats + (size_t)xg * 8;
#pragma unroll
      for (int k = 0; k < 7; k++) st[k] = s[k];
      st[7] = 0.0f;
    }
  } else {
    // prelude: wave per pixel p (p-indexed), early-exit masked
    int wave = tid >> 6;
    int p = (blk - 128) * 4 + wave;
    float mk = maskArr[p];
    if (mk == 0.0f) return;
    int b = p >> 13;
    int rem = p & (HWFM - 1);
    int i = rem >> 7;
    const float stepy = 1.0f / 63.0f;
    float yb = (i == 63) ? 1.0f : i * stepy;
    float t = xr[p] * (1.0f / 128.0f);   // exact recovery
    int y0i, y1i; float wy;
    gs_coord(yb, 32.0f, 63.0f, &y0i, &y1i, &wy);
    int x0i, x1i; float wx;
    gs_coord(t, 64.0f, 127.0f, &x0i, &x1i, &wx);

    int c2 = lane * 2;
    f16_2 q2 = *(const f16_2*)(refTf + (size_t)p * CFM + c2);
    int bo = b * HWFM;
    f16_2 a2 = *(const f16_2*)(tgtTf + (size_t)(bo + y0i * WFM + x0i) * CFM + c2);
    f16_2 b2 = *(const f16_2*)(tgtTf + (size_t)(bo + y0i * WFM + x1i) * CFM + c2);
    f16_2 cc2 = *(const f16_2*)(tgtTf + (size_t)(bo + y1i * WFM + x0i) * CFM + c2);
    f16_2 d2 = *(const f16_2*)(tgtTf + (size_t)(bo + y1i * WFM + x1i) * CFM + c2);

    float w00 = (1.0f - wx) * (1.0f - wy), w01 = wx * (1.0f - wy);
    float w10 = (1.0f - wx) * wy,          w11 = wx * wy;
    float q0 = (float)q2[0], q1 = (float)q2[1];
    float v0 = w00 * (float)a2[0] + w01 * (float)b2[0] + w10 * (float)cc2[0] + w11 * (float)d2[0];
    float v1 = w00 * (float)a2[1] + w01 * (float)b2[1] + w10 * (float)cc2[1] + w11 * (float)d2[1];

    float s0 = q0 * q0 + q1 * q1;
    float s1 = q0 * v0 + q1 * v1;
    float s2 = v0 * v0 + v1 * v1;
#pragma unroll
    for (int o = 32; o; o >>= 1) {
      s0 += __shfl_xor(s0, o, 64);
      s1 += __shfl_xor(s1, o, 64);
      s2 += __shfl_xor(s2, o, 64);
    }
    float inv = 1.0f / fmaxf(sqrtf(s0), 1e-12f);
    f16_2 qw; qw[0] = (_Float16)(q0 * inv); qw[1] = (_Float16)(q1 * inv);
    *(f16_2*)(QTf + (size_t)p * CFM + c2) = qw;
    if (lane == 0) {
      float lpos = (s1 * inv) / fmaxf(sqrtf(s2), 1e-12f);
      float lg0 = lpos / 0.07f;
      logit0[p] = lg0;
      S[p] = expf(lg0 - MSHIFT);
    }
  }
}

// ====== k_gemm (v4 structure + qb-reorder, MEASURED BEST = session record
// 115.2 us): XCD-affine 8 splits x 13 chunks, 64-row tile, 64-col LDS chunks
// (2 x 16 KB dbuf), global_load_lds with XOR-swizzled source. qb loads
// issued BEFORE the next-chunk stage (older than prefetch -> exp2 waits
// vmcnt(4), not a full drain). Probed basin (all worse): 13-col-interleaved
// +11us (r3), 16-col-split +6us (r5), asm-counted-vmcnt +50us (r7),
// 32-row-split +75us (r9, bank conflicts + halved MFMA amortization).
__global__ __launch_bounds__(256, 4) void k_gemm(
    const _Float16* __restrict__ QTf,     // [NPIX][128] (p-indexed)
    const _Float16* __restrict__ queueTf, // [6144][128]
    const _Float16* __restrict__ tgtTf,   // [NPIX][128]
    const float2* __restrict__ qeb,       // [6144]
    float* __restrict__ S, float* __restrict__ D,
    const int* __restrict__ count, const int* __restrict__ list) {
  __shared__ _Float16 Bs[2][64 * CFM];    // 2 x 16 KB
  __shared__ float Srow[64];
  int tid = threadIdx.x;
  int cnt = *count;
  int split = blockIdx.x & 7;             // XCD-affine column split
  int slot0 = (blockIdx.x >> 3) * 64;
  if (slot0 >= cnt) return;
  int wave = tid >> 6, lane = tid & 63;
  int quad = lane >> 4, l16 = lane & 15;
  int wm = wave >> 1, wn = wave & 1;
  int dbatch = split >> 2;                // this split's D chunk: batch
  int dxoff = (split & 3) * 64;           // and pixel/column offset

  if (tid < 64) Srow[tid] = 0.0f;

  // stage one 64-row B chunk (16 KB): 4 DMA insts/thread, 4 B-rows each.
  // LDS linear dest; swizzle via global source: LDS[r][c] = G[r][c ^ (r&7)]
  int lrow = lane >> 4, lchunk = lane & 15;
  auto stage = [&](const _Float16* bsrc, int buf) {
#pragma unroll
    for (int i = 0; i < 4; i++) {
      int rb = wave * 16 + i * 4;
      int r = rb + lrow;
      const _Float16* g = bsrc + (size_t)r * CFM + ((lchunk ^ (r & 7)) << 3);
      __builtin_amdgcn_global_load_lds(
          (const __attribute__((address_space(1))) void*)g,
          (__attribute__((address_space(3))) void*)(&Bs[buf][rb * CFM]),
          16, 0, 0);
    }
  };
  // B panel base for chunk ic: 0..11 = l_q cols, 12 = this split's D chunk
  auto bpanel = [&](int ic) -> const _Float16* {
    if (ic < 12) return queueTf + (size_t)(split * 768 + ic * 64) * CFM;
    return tgtTf + ((size_t)dbatch * HWFM + dxoff) * CFM;
  };

  stage(bpanel(0), 0);

  // A fragments via list indirection: 32 rows per wave (overlaps with DMA)
  f16_8 Af[2][4];
  int r0 = slot0 + wm * 32;
#pragma unroll
  for (int mt = 0; mt < 2; mt++) {
    int prow = list[min(r0 + mt * 16 + l16, cnt - 1)];
    const _Float16* arow = QTf + (size_t)prow * CFM + quad * 8;
#pragma unroll
    for (int ks = 0; ks < 4; ks++)
      Af[mt][ks] = *(const f16_8*)(arow + ks * 32);
  }
  // row batch ids (consumed by the D chunk's masked write)
  int pbv[2][4];
#pragma unroll
  for (int mt = 0; mt < 2; mt++)
#pragma unroll
    for (int r = 0; r < 4; r++)
      pbv[mt][r] = list[min(r0 + mt * 16 + quad * 4 + r, cnt - 1)] >> 13;

  __syncthreads();
  int cur = 0;
  float rowsum[2][4] = {{0.0f,0.0f,0.0f,0.0f},{0.0f,0.0f,0.0f,0.0f}};

  for (int ic = 0; ic < 13; ic++) {
    // qb FIRST: older than the stage DMA, so exp2's wait leaves the
    // prefetch in flight (vmcnt(4) not vmcnt(0)).
    float2 qb[2];
    if (ic < 12) {
      int n0 = split * 768 + ic * 64 + wn * 32;
      qb[0] = qeb[n0 + l16];
      qb[1] = qeb[n0 + 16 + l16];
    }
    if (ic + 1 < 13) stage(bpanel(ic + 1), cur ^ 1);
    f32_4 acc[2][2];
#pragma unroll
    for (int mt = 0; mt < 2; mt++)
#pragma unroll
      for (int nt = 0; nt < 2; nt++)
        acc[mt][nt] = (f32_4){0.0f, 0.0f, 0.0f, 0.0f};
#pragma unroll
    for (int ks = 0; ks < 4; ks++) {
      f16_8 Bk[2];
#pragma unroll
      for (int nt = 0; nt < 2; nt++) {
        int brow = wn * 32 + nt * 16 + l16;
        Bk[nt] = *(const f16_8*)(&Bs[cur][brow * CFM + ((ks * 32 + quad * 8) ^ ((brow & 7) * 8))]);
      }
#pragma unroll
      for (int mt = 0; mt < 2; mt++)
#pragma unroll
        for (int nt = 0; nt < 2; nt++)
          acc[mt][nt] = __builtin_amdgcn_mfma_f32_16x16x32_f16(Af[mt][ks], Bk[nt], acc[mt][nt], 0, 0, 0);
    }
    if (ic < 12) {
#pragma unroll
      for (int nt = 0; nt < 2; nt++)
#pragma unroll
        for (int mt = 0; mt < 2; mt++)
#pragma unroll
          for (int r = 0; r < 4; r++)
            rowsum[mt][r] += exp2f(fmaf(acc[mt][nt][r], qb[nt].x, qb[nt].y));
    } else {
#pragma unroll
      for (int mt = 0; mt < 2; mt++)
#pragma unroll
        for (int nt = 0; nt < 2; nt++)
#pragma unroll
          for (int r = 0; r < 4; r++) {
            int sl = slot0 + wm * 32 + mt * 16 + quad * 4 + r;
            int colL = dxoff + wn * 32 + nt * 16 + l16;
            if (sl < cnt && pbv[mt][r] == dbatch)
              D[(size_t)sl * 256 + colL] = acc[mt][nt][r];
          }
    }
    __syncthreads();
    cur ^= 1;
  }

#pragma unroll
  for (int mt = 0; mt < 2; mt++)
#pragma unroll
    for (int r = 0; r < 4; r++) {
      float vv = rowsum[mt][r];
      vv += __shfl_xor(vv, 1);
      vv += __shfl_xor(vv, 2);
      vv += __shfl_xor(vv, 4);
      vv += __shfl_xor(vv, 8);
      rowsum[mt][r] = vv;
    }
  if (l16 == 0) {
#pragma unroll
    for (int mt = 0; mt < 2; mt++)
#pragma unroll
      for (int r = 0; r < 4; r++)
        atomicAdd(&Srow[wm * 32 + mt * 16 + quad * 4 + r], rowsum[mt][r]);
  }
  __syncthreads();
  if (tid < 64) {
    int pr = slot0 + tid;
    if (pr < cnt) atomicAdd(&S[list[pr]], Srow[tid]);
  }
}

// -------- negatives: wave-per-pixel, scalar via D + stats decomposition ----
__global__ __launch_bounds__(256) void k_negatives_lite(
    const float* __restrict__ D, const float* __restrict__ stats,
    const float* __restrict__ xr, float* __restrict__ S,
    const int* __restrict__ count, const int* __restrict__ list,
    uint32_t k1a, uint32_t k1b, uint32_t k2a, uint32_t k2b) {
  int tid = threadIdx.x;
  int wave = tid >> 6, lane = tid & 63;
  int cnt = *count;
  int slot = blockIdx.x * 4 + wave;
  if (slot >= cnt) return;
  int p = list[slot];
  int b = p >> 13;
  float esum = 0.0f;
  if (lane < NNEG) {
    uint32_t e = (uint32_t)(p * NNEG + lane);
    uint32_t h0, h1;
    threefry2x32(k1a, k1b, e, e + (uint32_t)NE, &h0, &h1);
    uint32_t off = ((h0 % 24u) * 16u + (h1 % 24u)) % 24u;
    float mag = (float)(1u + off);
    uint32_t ub;
    {
      uint32_t a, bm;
      if (e < EHALF_U) { threefry2x32(k2a, k2b, e, e + EHALF_U, &a, &bm); ub = a; }
      else             { threefry2x32(k2a, k2b, e - EHALF_U, e, &a, &bm); ub = bm; }
    }
    float u = __uint_as_float((ub >> 9) | 0x3F800000u) - 1.0f;
    float sg = (u > 0.5f) ? 1.0f : ((u < 0.5f) ? -1.0f : 0.0f);

    float v = xr[p] + mag * sg;
    float r = fmodf(v, 128.0f);
    if (r < 0.0f) r += 128.0f;
    float fx = r * (1.0f / 128.0f);
    float fy = fx * (1.0f / 64.0f);
    int x0i, x1i, y0i, y1i; float wx, wy;
    gs_coord(fx, 64.0f, 127.0f, &x0i, &x1i, &wx);
    gs_coord(fy, 32.0f, 63.0f, &y0i, &y1i, &wy);

    const float* Dp = D + (size_t)slot * 256;
    float d00 = Dp[x0i], d01 = Dp[x1i];
    float d10 = Dp[128 + x0i], d11 = Dp[128 + x1i];
    float u0 = 1.0f - wy, u1 = wy;
    float dv0 = u0 * d00 + u1 * d10;
    float dv1 = u0 * d01 + u1 * d11;
    float dot = (1.0f - wx) * dv0 + wx * dv1;

    const float* st0 = stats + (size_t)(b * 128 + x0i) * 8;
    const float* st1 = stats + (size_t)(b * 128 + x1i) * 8;
    float4 sa = *(const float4*)st0;
    float4 sb = *(const float4*)(st0 + 4);
    float4 sc = *(const float4*)st1;
    float a0 = u0 * u0, a1 = u0 * u1, a2 = u1 * u1;
    float nB0 = a0 * sa.x + 2.0f * a1 * sa.y + a2 * sa.z;
    float nB1 = a0 * sc.x + 2.0f * a1 * sc.y + a2 * sc.z;
    float cB  = a0 * sa.w + a1 * (sb.x + sb.y) + a2 * sb.z;
    float wx0 = 1.0f - wx;
    float nsq = wx0 * wx0 * nB0 + 2.0f * wx * wx0 * cB + wx * wx * nB1;
    float ln = dot / fmaxf(sqrtf(fmaxf(nsq, 0.0f)), 1e-12f);
    esum = __expf(ln * (1.0f / 0.07f) - MSHIFT);
  }
#pragma unroll
  for (int o = 32; o; o >>= 1) esum += __shfl_xor(esum, o, 64);
  if (lane == 0) atomicAdd(&S[p], esum);
}

// -------- finalize: 16 blocks, per-block deterministic tree, cross-block
// double atomics. 16 device-scope fences total (cheap); do NOT scale this
// to thousands of blocks — r7 measured ~27 ns/block-fence serialized
// (per-XCD L2 writeback) = 112 us at 4096 blocks.
__global__ __launch_bounds__(1024) void k_finalize(
    const float* __restrict__ S, const float* __restrict__ logit0,
    const float* __restrict__ maskArr, float* __restrict__ out,
    double* __restrict__ dacc, int* __restrict__ dctr) {
  int tid = threadIdx.x;
  const float cmask = logf(6061.0f);
  int p = blockIdx.x * 1024 + tid;
  float term = (maskArr[p] > 0.0f) ? (logf(S[p]) + MSHIFT - logit0[p]) : cmask;
  double acc = (double)term;
#pragma unroll
  for (int off = 32; off; off >>= 1) acc += __shfl_down(acc, off, 64);
  __shared__ double sd[16];
  if ((tid & 63) == 0) sd[tid >> 6] = acc;
  __syncthreads();
  if (tid == 0) {
    double tot = 0.0;
    for (int w = 0; w < 16; w++) tot += sd[w];
    atomicAdd(dacc, tot);
    __threadfence();
    int old = atomicAdd(dctr, 1);
    if (old == 15) {
      __threadfence();
      out[0] = (float)(*(volatile double*)dacc / (double)NPIX);
    }
  }
}

extern "C" void kernel_launch(void* const* d_in, const int* in_sizes, int n_in,
                              void* d_out, int out_size, void* d_ws, size_t ws_size,
                              hipStream_t stream) {
  const float* ref   = (const float*)d_in[0];
  const float* tgt   = (const float*)d_in[1];
  const float* tl    = (const float*)d_in[2];
  const float* tr    = (const float*)d_in[3];
  const float* queue = (const float*)d_in[4];
  float* out = (float*)d_out;
  float* ws = (float*)d_ws;

  float2* qeb = (float2*)ws;                 // 6144 float2 -> 12288 floats
  float* S    = ws + 12288;                  // 16384
  float* lg0  = ws + 28672;                  // 16384
  float* mk   = ws + 45056;                  // 16384
  float* xr   = ws + 61440;                  // 16384 -> 77824
  int* count  = (int*)(ws + 77824);          // 1
  double* dacc = (double*)(ws + 77826);      // 8B-aligned (77826*4 % 8 == 0)
  int* dctr   = (int*)(ws + 77828);          // 1
  int* list   = (int*)(ws + 77840);          // 16384 -> 94224
  _Float16* QTf     = (_Float16*)(ws + 94464);    // NPIX*128 f16 (p-indexed)
  _Float16* queueTf = (_Float16*)(ws + 1143040);  // 6144*128 f16
  _Float16* tgtTf   = (_Float16*)(ws + 1536256);  // NPIX*128 f16
  _Float16* refTf   = (_Float16*)(ws + 2584832);  // NPIX*128 f16
  float* stats = ws + 3633408;                    // 2048
  float* D     = ws + 3635456;                    // NPIX*256 f32

  // JAX: k1, k2 = split(key(1234))
  uint32_t b0o0, b0o1, b1o0, b1o1;
  threefry2x32(0u, 1234u, 0u, 2u, &b0o0, &b0o1);
  threefry2x32(0u, 1234u, 1u, 3u, &b1o0, &b1o1);
  uint32_t k1a = b0o0, k1b = b1o0, k2a = b0o1, k2b = b1o1;

  k_A<<<dim3(2520), dim3(256), 0, stream>>>(ref, tgt, queue, tl, tr,
                                            refTf, tgtTf, queueTf, qeb, mk, xr,
                                            dacc, dctr, count);
  k_B<<<dim3(128 + 4096), dim3(256), 0, stream>>>(refTf, tgtTf, QTf, stats,
                                                  mk, xr, S, lg0, count, list);
  // 8 XCD-affine splits x 256 row-blocks, 1-D grid (split = bid & 7)
  k_gemm<<<dim3(2048), dim3(256), 0, stream>>>(QTf, queueTf, tgtTf, qeb,
                                               S, D, count, list);
  k_negatives_lite<<<dim3(NPIX / 4), dim3(256), 0, stream>>>(D, stats, xr, S, count, list,
                                                             k1a, k1b, k2a, k2b);
  k_finalize<<<dim3(16), dim3(1024), 0, stream>>>(S, lg0, mk, out, dacc, dctr);
}